// Round 16
// baseline (1232.043 us; speedup 1.0000x reference)
//
#include <hip/hip_runtime.h>
#include <stdint.h>

#define SEQ   256
#define BATCH 256
#define HID   1024
#define NCLS  10

// 128 WGs = 8 batch-groups (32 batch rows) x 16 hid-blocks (64 hid rows).
// Transposed recurrence: C = W^T (A-operand, regs) x h^T (B-operand, global).
// Tagged-data exchange (r7-r15 proven): per-32-bit-word step tag in bf16 LSB;
// fire-and-forget write-through stores; consumers poll the data itself;
// lgkm-only barrier; x in LDS.
// r16 = r15 + ONE change: calibrated pre-poll delay. Non-owner waves reach
// the poll ~0.05us after the barrier but remote stores are only visible at
// ~0.7us -> their first round ALWAYS missed (a wasted RT + retry). A role-
// dependent s_sleep (non-owners ~14 units, owners ~3) aligns the first round
// with store visibility. Delay-only: adds no traffic at the wrong time
// (the r13/r14 failure mode), worst case idles time that was dead anyway.
#define NWG     128
#define THREADS 512
#define PLANEB  (32 * 16 * 64 * 16)   // 32 kstacks x 16 bfrags x 64 lanes x 16B

typedef __attribute__((ext_vector_type(8))) short bf16x8;
typedef __attribute__((ext_vector_type(4))) float f32x4;
typedef __attribute__((ext_vector_type(4))) unsigned int u32x4;

__device__ __forceinline__ unsigned short f2bf(float f) {
  unsigned u = __builtin_bit_cast(unsigned, f);
  u = (u + 0x7FFFu + ((u >> 16) & 1u)) >> 16;
  return (unsigned short)u;
}
__device__ __forceinline__ float bf2f(unsigned short h) {
  unsigned u = ((unsigned)h) << 16;
  return __builtin_bit_cast(float, u);
}
__device__ __forceinline__ float fast_tanh(float x) {
  float ax = __builtin_fabsf(x);
  float e = __expf(2.0f * ax);
  float t = 1.0f - 2.0f / (e + 1.0f);
  return __builtin_copysignf(t, x);
}
// tag alternates per plane reuse; first write of each plane is 1 (0xAA poison
// LSB=0 rejected). Skew is structurally bounded to 1 step (r7/r8 argument).
__device__ __forceinline__ unsigned tag_of(unsigned t) {
  return ((t >> 1) & 1u) ^ 1u;
}

// 8 tagged fragment loads (r10-r15-proven syntax). NO wait inside.
#define ISSUE8(A0,A1,A2,A3,A4,A5,A6,A7, B0,B1,B2,B3)                           \
  asm volatile(                                                                \
    "global_load_dwordx4 %0, %8, off sc0 sc1\n\t"                              \
    "global_load_dwordx4 %1, %8, off offset:1024 sc0 sc1\n\t"                  \
    "global_load_dwordx4 %2, %9, off sc0 sc1\n\t"                              \
    "global_load_dwordx4 %3, %9, off offset:1024 sc0 sc1\n\t"                  \
    "global_load_dwordx4 %4, %10, off sc0 sc1\n\t"                             \
    "global_load_dwordx4 %5, %10, off offset:1024 sc0 sc1\n\t"                 \
    "global_load_dwordx4 %6, %11, off sc0 sc1\n\t"                             \
    "global_load_dwordx4 %7, %11, off offset:1024 sc0 sc1"                     \
    : "=&v"(A0),"=&v"(A1),"=&v"(A2),"=&v"(A3),                                 \
      "=&v"(A4),"=&v"(A5),"=&v"(A6),"=&v"(A7)                                  \
    : "v"(B0),"v"(B1),"v"(B2),"v"(B3)                                          \
    : "memory")

#define WAIT0() do { asm volatile("s_waitcnt vmcnt(0)" ::: "memory");          \
                     __builtin_amdgcn_sched_barrier(0); } while (0)

#define CHECK8(A0,A1,A2,A3,A4,A5,A6,A7, TAU) ({                                \
  unsigned vb_ = ((A0[0]^TAU)|(A0[1]^TAU)|(A0[2]^TAU)|(A0[3]^TAU)|             \
                  (A1[0]^TAU)|(A1[1]^TAU)|(A1[2]^TAU)|(A1[3]^TAU)|             \
                  (A2[0]^TAU)|(A2[1]^TAU)|(A2[2]^TAU)|(A2[3]^TAU)|             \
                  (A3[0]^TAU)|(A3[1]^TAU)|(A3[2]^TAU)|(A3[3]^TAU)|             \
                  (A4[0]^TAU)|(A4[1]^TAU)|(A4[2]^TAU)|(A4[3]^TAU)|             \
                  (A5[0]^TAU)|(A5[1]^TAU)|(A5[2]^TAU)|(A5[3]^TAU)|             \
                  (A6[0]^TAU)|(A6[1]^TAU)|(A6[2]^TAU)|(A6[3]^TAU)|             \
                  (A7[0]^TAU)|(A7[1]^TAU)|(A7[2]^TAU)|(A7[3]^TAU)) & 1u;       \
  __all((int)(vb_ == 0)); })

// LDS-only barrier: ds ops drained; fire-and-forget stores fly across
#define BARRIER() asm volatile("s_waitcnt lgkmcnt(0)\n\ts_barrier" ::: "memory")

__global__ __launch_bounds__(THREADS, 1) void rnn_r16(
    const float* __restrict__ x, const float* __restrict__ Whx,
    const float* __restrict__ Whh, const float* __restrict__ Wph,
    const float* __restrict__ bh, const float* __restrict__ bp,
    float* __restrict__ out, unsigned char* __restrict__ ws)
{
  __shared__ f32x4 red[2][4][2][7][64];   // 112 KiB dbuf kt-split reduction
  __shared__ float x_lds[32][257];        // 32.9 KiB padded x slice

  const int tid  = threadIdx.x;
  const int lane = tid & 63;
  const int wv   = tid >> 6;          // 0..7
  const int l15  = lane & 15;
  const int q    = lane >> 4;

  const int gb = blockIdx.x >> 4;     // batch group 0..7 (rows gb*32..+31)
  const int s  = blockIdx.x & 15;     // hid block 0..15 (hid s*64..+63)

  unsigned char* p0 = ws;             // h^T plane 0 (512 KiB)
  unsigned char* p1 = ws + PLANEB;    // h^T plane 1

  // ---- prologue: x slice -> LDS (keeps owner epilogue off the vmem queue)
  for (int idx = tid; idx < 32 * 256; idx += THREADS) {
    int row = idx >> 8, tt = idx & 255;
    x_lds[row][tt] = x[(size_t)(gb * 32 + row) * SEQ + tt];
  }

  // ---- prologue: this wave's W^T A-fragments (hi+lo) into registers
  bf16x8 whi[4][4], wlo[4][4];
#pragma unroll
  for (int i = 0; i < 4; ++i) {
    const int ks = wv * 4 + i;
#pragma unroll
    for (int rt = 0; rt < 4; ++rt) {
      const int n = s * 64 + rt * 16 + l15;
#pragma unroll
      for (int j = 0; j < 8; ++j) {
        int k = ks * 32 + 4 * q + (j & 3) + 16 * (j >> 2);
        float w = Whh[(size_t)k * HID + n];
        unsigned short hi = f2bf(w);
        whi[i][rt][j] = (short)hi;
        wlo[i][rt][j] = (short)f2bf(w - bf2f(hi));
      }
    }
  }

  // owner mapping (r11-proven): waves 0..3 own one full 16B fragment each
  const int u_o  = wv >> 1, bt_oo = wv & 1;
  const int u_c  = (wv < 4) ? u_o : 0;   // clamp for unused wv>=4 vector loads
  float4 whxA, whxB, bhA, bhB;
  whxA = *(const float4*)(Whx + s * 64 + (2 * u_c) * 16 + q * 4);
  whxB = *(const float4*)(Whx + s * 64 + (2 * u_c + 1) * 16 + q * 4);
  bhA  = *(const float4*)(bh  + s * 64 + (2 * u_c) * 16 + q * 4);
  bhB  = *(const float4*)(bh  + s * 64 + (2 * u_c + 1) * 16 + q * 4);
  const size_t soff = ((size_t)((s * 2 + u_c) * 16 + gb * 2 + bt_oo) * 64 + lane) * 16;
  volatile u32x4* st0 = (volatile u32x4*)(p0 + soff);
  volatile u32x4* st1 = (volatile u32x4*)(p1 + soff);

  // per-wave fragment offsets within a plane
  const size_t oA0 = ((size_t)((wv * 4 + 0) * 16 + gb * 2) * 64 + lane) * 16;
  const size_t oA1 = ((size_t)((wv * 4 + 1) * 16 + gb * 2) * 64 + lane) * 16;
  const size_t oA2 = ((size_t)((wv * 4 + 2) * 16 + gb * 2) * 64 + lane) * 16;
  const size_t oA3 = ((size_t)((wv * 4 + 3) * 16 + gb * 2) * 64 + lane) * 16;

  __syncthreads();   // x_lds ready + full drain: vmem queue starts empty

#define MSTEP(F, I, BT)                                                        \
      { bf16x8 a_ = __builtin_bit_cast(bf16x8, F);                             \
        acc[0][BT] = __builtin_amdgcn_mfma_f32_16x16x32_bf16(whi[I][0], a_, acc[0][BT], 0, 0, 0); \
        acc[0][BT] = __builtin_amdgcn_mfma_f32_16x16x32_bf16(wlo[I][0], a_, acc[0][BT], 0, 0, 0); \
        acc[1][BT] = __builtin_amdgcn_mfma_f32_16x16x32_bf16(whi[I][1], a_, acc[1][BT], 0, 0, 0); \
        acc[1][BT] = __builtin_amdgcn_mfma_f32_16x16x32_bf16(wlo[I][1], a_, acc[1][BT], 0, 0, 0); \
        acc[2][BT] = __builtin_amdgcn_mfma_f32_16x16x32_bf16(whi[I][2], a_, acc[2][BT], 0, 0, 0); \
        acc[2][BT] = __builtin_amdgcn_mfma_f32_16x16x32_bf16(wlo[I][2], a_, acc[2][BT], 0, 0, 0); \
        acc[3][BT] = __builtin_amdgcn_mfma_f32_16x16x32_bf16(whi[I][3], a_, acc[3][BT], 0, 0, 0); \
        acc[3][BT] = __builtin_amdgcn_mfma_f32_16x16x32_bf16(wlo[I][3], a_, acc[3][BT], 0, 0, 0); }
#define MBLOCK(F0,F1,F2,F3,F4,F5,F6,F7)                                        \
      MSTEP(F0, 0, 0) MSTEP(F1, 0, 1) MSTEP(F2, 1, 0) MSTEP(F3, 1, 1)          \
      MSTEP(F4, 2, 0) MSTEP(F5, 2, 1) MSTEP(F6, 3, 0) MSTEP(F7, 3, 1)

  // ---- sequential time steps
  for (int t = 0; t < SEQ; ++t) {
    const unsigned tauW = tag_of((unsigned)t);
    const int buf = t & 1;

    f32x4 acc[4][2];
#pragma unroll
    for (int rt = 0; rt < 4; ++rt)
#pragma unroll
      for (int bt = 0; bt < 2; ++bt) acc[rt][bt] = (f32x4){0.f, 0.f, 0.f, 0.f};

    if (t > 0) {
      const unsigned tauR = tag_of((unsigned)(t - 1));
      const unsigned char* rp = (t & 1) ? p0 : p1;   // plane of h_{t-1}
      const unsigned char* b0 = rp + oA0;
      const unsigned char* b1 = rp + oA1;
      const unsigned char* b2 = rp + oA2;
      const unsigned char* b3 = rp + oA3;
      u32x4 f0, f1, f2, f3, f4, f5, f6, f7;

      // ---- r16: calibrated pre-poll delay. Remote stores become visible
      // ~0.7us after the barrier; non-owners arrive here ~0.05us after it
      // (owners ~0.35us, having done reduce+store). Delay-only alignment:
      // no extra traffic, worst case idles otherwise-dead time.
      if (wv < 4) __builtin_amdgcn_s_sleep(3);    // ~192 cyc  (~0.08 us)
      else        __builtin_amdgcn_s_sleep(14);   // ~896 cyc  (~0.37 us)

      // r11/r15-proven single-phase poll: full loads + 32-tag verify
      for (;;) {
        ISSUE8(f0,f1,f2,f3,f4,f5,f6,f7, b0,b1,b2,b3);
        WAIT0();
        if (CHECK8(f0,f1,f2,f3,f4,f5,f6,f7, tauR)) break;
        __builtin_amdgcn_s_sleep(1);
      }
      MBLOCK(f0,f1,f2,f3,f4,f5,f6,f7)
    }

    // ---- kt-split partials for non-owned tiles -> red[buf] (r11-proven)
#pragma unroll
    for (int T = 0; T < 8; ++T) {
      const int rt = T >> 1, bt = T & 1;
      const int o = (rt & 2) | bt;
      if (o != wv) {
        const int slot = (wv > o) ? (wv - 1) : wv;
        red[buf][rt][bt][slot][lane] = acc[rt][bt];
      }
    }
    BARRIER();   // lgkm-only: store acks never gate the barrier

    // ---- owner waves 0..3: reduce both tiles, epilogue, one 16B store
    if (wv < 4) {
      f32x4 sA = acc[2 * u_c][bt_oo];
      f32x4 sB = acc[2 * u_c + 1][bt_oo];
#pragma unroll
      for (int pr = 0; pr < 7; ++pr) {
        sA += red[buf][2 * u_c][bt_oo][pr][lane];
        sB += red[buf][2 * u_c + 1][bt_oo][pr][lane];
      }
      const float xb = x_lds[bt_oo * 16 + l15][t];
      const float a0 = fast_tanh(sA[0] + xb * whxA.x + bhA.x);
      const float a1 = fast_tanh(sA[1] + xb * whxA.y + bhA.y);
      const float a2 = fast_tanh(sA[2] + xb * whxA.z + bhA.z);
      const float a3 = fast_tanh(sA[3] + xb * whxA.w + bhA.w);
      const float c0 = fast_tanh(sB[0] + xb * whxB.x + bhB.x);
      const float c1 = fast_tanh(sB[1] + xb * whxB.y + bhB.y);
      const float c2 = fast_tanh(sB[2] + xb * whxB.z + bhB.z);
      const float c3 = fast_tanh(sB[3] + xb * whxB.w + bhB.w);
      u32x4 stv;
      stv[0] = (((unsigned)f2bf(a0) | ((unsigned)f2bf(a1) << 16)) & ~1u) | tauW;
      stv[1] = (((unsigned)f2bf(a2) | ((unsigned)f2bf(a3) << 16)) & ~1u) | tauW;
      stv[2] = (((unsigned)f2bf(c0) | ((unsigned)f2bf(c1) << 16)) & ~1u) | tauW;
      stv[3] = (((unsigned)f2bf(c2) | ((unsigned)f2bf(c3) << 16)) & ~1u) | tauW;
      if (t & 1) *st1 = stv; else *st0 = stv;   // fire-and-forget write-through
    }
  }

  // ---- final projection (one WG per batch-group): out = h_last @ Wph + bp
  if (s != 0) return;
  {
    const unsigned tauF = tag_of(255u);   // = 0
    u32x4 hf[4][2];
    for (;;) {
#pragma unroll
      for (int i = 0; i < 4; ++i)
#pragma unroll
        for (int bt = 0; bt < 2; ++bt)
          hf[i][bt] = *(const volatile u32x4*)
              (p1 + ((size_t)((wv * 4 + i) * 16 + gb * 2 + bt) * 64 + lane) * 16);
      unsigned bad = 0;
#pragma unroll
      for (int i = 0; i < 4; ++i)
#pragma unroll
        for (int bt = 0; bt < 2; ++bt)
#pragma unroll
          for (int w = 0; w < 4; ++w) bad |= (hf[i][bt][w] ^ tauF) & 1u;
      if (__all((int)(bad == 0))) break;
      __builtin_amdgcn_s_sleep(2);
    }

    float pr0[NCLS], pr1[NCLS];
#pragma unroll
    for (int c = 0; c < NCLS; ++c) { pr0[c] = 0.f; pr1[c] = 0.f; }
#pragma unroll
    for (int i = 0; i < 4; ++i) {
      const int ks = wv * 4 + i;
#pragma unroll
      for (int bt = 0; bt < 2; ++bt) {
#pragma unroll
        for (int w = 0; w < 4; ++w) {
          unsigned word = hf[i][bt][w];
#pragma unroll
          for (int h2 = 0; h2 < 2; ++h2) {
            int j = 2 * w + h2;
            int k = ks * 32 + 4 * q + (j & 3) + 16 * (j >> 2);
            float hv = bf2f((unsigned short)(h2 ? (word >> 16) : (word & 0xffffu)));
            const float* wrow = Wph + (size_t)k * NCLS;
#pragma unroll
            for (int c = 0; c < NCLS; ++c) {
              if (bt == 0) pr0[c] += hv * wrow[c];
              else         pr1[c] += hv * wrow[c];
            }
          }
        }
      }
    }
#pragma unroll
    for (int c = 0; c < NCLS; ++c) {
      pr0[c] += __shfl_xor(pr0[c], 16, 64); pr0[c] += __shfl_xor(pr0[c], 32, 64);
      pr1[c] += __shfl_xor(pr1[c], 16, 64); pr1[c] += __shfl_xor(pr1[c], 32, 64);
    }
    float* projl = (float*)&red[0][0][0][0][0];   // reuse LDS
    if (q == 0) {
#pragma unroll
      for (int c = 0; c < NCLS; ++c) {
        projl[((wv * 2 + 0) * 16 + l15) * NCLS + c] = pr0[c];
        projl[((wv * 2 + 1) * 16 + l15) * NCLS + c] = pr1[c];
      }
    }
    __syncthreads();
    if (tid < 32 * NCLS) {
      int bl = tid / NCLS, c = tid - bl * NCLS;
      float sum = bp[c];
#pragma unroll
      for (int w = 0; w < 8; ++w)
        sum += projl[((w * 2 + (bl >> 4)) * 16 + (bl & 15)) * NCLS + c];
      out[(size_t)(gb * 32 + bl) * NCLS + c] = sum;
    }
  }
}

extern "C" void kernel_launch(void* const* d_in, const int* in_sizes, int n_in,
                              void* d_out, int out_size, void* d_ws, size_t ws_size,
                              hipStream_t stream) {
  const float* x   = (const float*)d_in[0];
  const float* Whx = (const float*)d_in[1];
  const float* Whh = (const float*)d_in[2];
  const float* Wph = (const float*)d_in[3];
  const float* bh  = (const float*)d_in[4];
  const float* bp  = (const float*)d_in[5];

  // no memset: tags self-validate against poison / stale replay data
  hipLaunchKernelGGL(rnn_r16, dim3(NWG), dim3(THREADS), 0, stream,
                     x, Whx, Whh, Wph, bh, bp,
                     (float*)d_out, (unsigned char*)d_ws);
}

// Round 17
// 1205.338 us; speedup vs baseline: 1.0222x; 1.0222x over previous
//
#include <hip/hip_runtime.h>
#include <stdint.h>

#define SEQ   256
#define BATCH 256
#define HID   1024
#define NCLS  10

// 128 WGs = 8 batch-groups (32 batch rows) x 16 hid-blocks (64 hid rows).
// Transposed recurrence: C = W^T (A-operand, regs) x h^T (B-operand, global).
// Tagged-data exchange (r7-r15 proven). r17: PHASE-LOCKED CLOCK GATING --
// steps t=1..17 run the r15 poll protocol while measuring the step period via
// s_memrealtime (chip-global, constant-rate, zero-traffic). From t>17 each WG
// waits until the absolute schedule T_B+(t-17)*(3/4*avg) BEFORE polling:
// detection jitter is absorbed by idle waiting instead of wasted poll rounds,
// and poll bursts stop congesting the MALL. The tagged poll remains as the
// correctness fallback -- early WGs burn one retry, late WGs skip the gate
// entirely (degenerates to r15). Failure bounded at r15 perf.
#define NWG     128
#define THREADS 512
#define PLANEB  (32 * 16 * 64 * 16)   // 32 kstacks x 16 bfrags x 64 lanes x 16B
#define CAL_T0  1
#define CAL_T1  17                    // 16-step calibration window

typedef __attribute__((ext_vector_type(8))) short bf16x8;
typedef __attribute__((ext_vector_type(4))) float f32x4;
typedef __attribute__((ext_vector_type(4))) unsigned int u32x4;

__device__ __forceinline__ unsigned short f2bf(float f) {
  unsigned u = __builtin_bit_cast(unsigned, f);
  u = (u + 0x7FFFu + ((u >> 16) & 1u)) >> 16;
  return (unsigned short)u;
}
__device__ __forceinline__ float bf2f(unsigned short h) {
  unsigned u = ((unsigned)h) << 16;
  return __builtin_bit_cast(float, u);
}
__device__ __forceinline__ float fast_tanh(float x) {
  float ax = __builtin_fabsf(x);
  float e = __expf(2.0f * ax);
  float t = 1.0f - 2.0f / (e + 1.0f);
  return __builtin_copysignf(t, x);
}
__device__ __forceinline__ unsigned tag_of(unsigned t) {
  return ((t >> 1) & 1u) ^ 1u;
}
__device__ __forceinline__ unsigned long long rtc() {
  unsigned long long v;
  asm volatile("s_memrealtime %0\n\ts_waitcnt lgkmcnt(0)" : "=s"(v));
  return v;
}

// 8 tagged fragment loads (r10-r15-proven syntax). NO wait inside.
#define ISSUE8(A0,A1,A2,A3,A4,A5,A6,A7, B0,B1,B2,B3)                           \
  asm volatile(                                                                \
    "global_load_dwordx4 %0, %8, off sc0 sc1\n\t"                              \
    "global_load_dwordx4 %1, %8, off offset:1024 sc0 sc1\n\t"                  \
    "global_load_dwordx4 %2, %9, off sc0 sc1\n\t"                              \
    "global_load_dwordx4 %3, %9, off offset:1024 sc0 sc1\n\t"                  \
    "global_load_dwordx4 %4, %10, off sc0 sc1\n\t"                             \
    "global_load_dwordx4 %5, %10, off offset:1024 sc0 sc1\n\t"                 \
    "global_load_dwordx4 %6, %11, off sc0 sc1\n\t"                             \
    "global_load_dwordx4 %7, %11, off offset:1024 sc0 sc1"                     \
    : "=&v"(A0),"=&v"(A1),"=&v"(A2),"=&v"(A3),                                 \
      "=&v"(A4),"=&v"(A5),"=&v"(A6),"=&v"(A7)                                  \
    : "v"(B0),"v"(B1),"v"(B2),"v"(B3)                                          \
    : "memory")

#define WAIT0() do { asm volatile("s_waitcnt vmcnt(0)" ::: "memory");          \
                     __builtin_amdgcn_sched_barrier(0); } while (0)

#define CHECK8(A0,A1,A2,A3,A4,A5,A6,A7, TAU) ({                                \
  unsigned vb_ = ((A0[0]^TAU)|(A0[1]^TAU)|(A0[2]^TAU)|(A0[3]^TAU)|             \
                  (A1[0]^TAU)|(A1[1]^TAU)|(A1[2]^TAU)|(A1[3]^TAU)|             \
                  (A2[0]^TAU)|(A2[1]^TAU)|(A2[2]^TAU)|(A2[3]^TAU)|             \
                  (A3[0]^TAU)|(A3[1]^TAU)|(A3[2]^TAU)|(A3[3]^TAU)|             \
                  (A4[0]^TAU)|(A4[1]^TAU)|(A4[2]^TAU)|(A4[3]^TAU)|             \
                  (A5[0]^TAU)|(A5[1]^TAU)|(A5[2]^TAU)|(A5[3]^TAU)|             \
                  (A6[0]^TAU)|(A6[1]^TAU)|(A6[2]^TAU)|(A6[3]^TAU)|             \
                  (A7[0]^TAU)|(A7[1]^TAU)|(A7[2]^TAU)|(A7[3]^TAU)) & 1u;       \
  __all((int)(vb_ == 0)); })

// LDS-only barrier: ds ops drained; fire-and-forget stores fly across
#define BARRIER() asm volatile("s_waitcnt lgkmcnt(0)\n\ts_barrier" ::: "memory")

__global__ __launch_bounds__(THREADS, 1) void rnn_r17(
    const float* __restrict__ x, const float* __restrict__ Whx,
    const float* __restrict__ Whh, const float* __restrict__ Wph,
    const float* __restrict__ bh, const float* __restrict__ bp,
    float* __restrict__ out, unsigned char* __restrict__ ws)
{
  __shared__ f32x4 red[2][4][2][7][64];   // 112 KiB dbuf kt-split reduction
  __shared__ float x_lds[32][257];        // 32.9 KiB padded x slice

  const int tid  = threadIdx.x;
  const int lane = tid & 63;
  const int wv   = tid >> 6;          // 0..7
  const int l15  = lane & 15;
  const int q    = lane >> 4;

  const int gb = blockIdx.x >> 4;     // batch group 0..7 (rows gb*32..+31)
  const int s  = blockIdx.x & 15;     // hid block 0..15 (hid s*64..+63)

  unsigned char* p0 = ws;             // h^T plane 0 (512 KiB)
  unsigned char* p1 = ws + PLANEB;    // h^T plane 1

  // ---- prologue: x slice -> LDS
  for (int idx = tid; idx < 32 * 256; idx += THREADS) {
    int row = idx >> 8, tt = idx & 255;
    x_lds[row][tt] = x[(size_t)(gb * 32 + row) * SEQ + tt];
  }

  // ---- prologue: this wave's W^T A-fragments (hi+lo) into registers
  bf16x8 whi[4][4], wlo[4][4];
#pragma unroll
  for (int i = 0; i < 4; ++i) {
    const int ks = wv * 4 + i;
#pragma unroll
    for (int rt = 0; rt < 4; ++rt) {
      const int n = s * 64 + rt * 16 + l15;
#pragma unroll
      for (int j = 0; j < 8; ++j) {
        int k = ks * 32 + 4 * q + (j & 3) + 16 * (j >> 2);
        float w = Whh[(size_t)k * HID + n];
        unsigned short hi = f2bf(w);
        whi[i][rt][j] = (short)hi;
        wlo[i][rt][j] = (short)f2bf(w - bf2f(hi));
      }
    }
  }

  // owner mapping (r11-proven): waves 0..3 own one full 16B fragment each
  const int u_o  = wv >> 1, bt_oo = wv & 1;
  const int u_c  = (wv < 4) ? u_o : 0;
  float4 whxA, whxB, bhA, bhB;
  whxA = *(const float4*)(Whx + s * 64 + (2 * u_c) * 16 + q * 4);
  whxB = *(const float4*)(Whx + s * 64 + (2 * u_c + 1) * 16 + q * 4);
  bhA  = *(const float4*)(bh  + s * 64 + (2 * u_c) * 16 + q * 4);
  bhB  = *(const float4*)(bh  + s * 64 + (2 * u_c + 1) * 16 + q * 4);
  const size_t soff = ((size_t)((s * 2 + u_c) * 16 + gb * 2 + bt_oo) * 64 + lane) * 16;
  volatile u32x4* st0 = (volatile u32x4*)(p0 + soff);
  volatile u32x4* st1 = (volatile u32x4*)(p1 + soff);

  // per-wave fragment offsets within a plane
  const size_t oA0 = ((size_t)((wv * 4 + 0) * 16 + gb * 2) * 64 + lane) * 16;
  const size_t oA1 = ((size_t)((wv * 4 + 1) * 16 + gb * 2) * 64 + lane) * 16;
  const size_t oA2 = ((size_t)((wv * 4 + 2) * 16 + gb * 2) * 64 + lane) * 16;
  const size_t oA3 = ((size_t)((wv * 4 + 3) * 16 + gb * 2) * 64 + lane) * 16;

  __syncthreads();   // x_lds ready + full drain

#define MSTEP(F, I, BT)                                                        \
      { bf16x8 a_ = __builtin_bit_cast(bf16x8, F);                             \
        acc[0][BT] = __builtin_amdgcn_mfma_f32_16x16x32_bf16(whi[I][0], a_, acc[0][BT], 0, 0, 0); \
        acc[0][BT] = __builtin_amdgcn_mfma_f32_16x16x32_bf16(wlo[I][0], a_, acc[0][BT], 0, 0, 0); \
        acc[1][BT] = __builtin_amdgcn_mfma_f32_16x16x32_bf16(whi[I][1], a_, acc[1][BT], 0, 0, 0); \
        acc[1][BT] = __builtin_amdgcn_mfma_f32_16x16x32_bf16(wlo[I][1], a_, acc[1][BT], 0, 0, 0); \
        acc[2][BT] = __builtin_amdgcn_mfma_f32_16x16x32_bf16(whi[I][2], a_, acc[2][BT], 0, 0, 0); \
        acc[2][BT] = __builtin_amdgcn_mfma_f32_16x16x32_bf16(wlo[I][2], a_, acc[2][BT], 0, 0, 0); \
        acc[3][BT] = __builtin_amdgcn_mfma_f32_16x16x32_bf16(whi[I][3], a_, acc[3][BT], 0, 0, 0); \
        acc[3][BT] = __builtin_amdgcn_mfma_f32_16x16x32_bf16(wlo[I][3], a_, acc[3][BT], 0, 0, 0); }
#define MBLOCK(F0,F1,F2,F3,F4,F5,F6,F7)                                        \
      MSTEP(F0, 0, 0) MSTEP(F1, 0, 1) MSTEP(F2, 1, 0) MSTEP(F3, 1, 1)          \
      MSTEP(F4, 2, 0) MSTEP(F5, 2, 1) MSTEP(F6, 3, 0) MSTEP(F7, 3, 1)

  // clock-gate state (uniform scalars)
  unsigned long long TA = 0, TB = 0, dstep = 0;

  // ---- sequential time steps
  for (int t = 0; t < SEQ; ++t) {
    const unsigned tauW = tag_of((unsigned)t);
    const int buf = t & 1;

    f32x4 acc[4][2];
#pragma unroll
    for (int rt = 0; rt < 4; ++rt)
#pragma unroll
      for (int bt = 0; bt < 2; ++bt) acc[rt][bt] = (f32x4){0.f, 0.f, 0.f, 0.f};

    if (t > 0) {
      const unsigned tauR = tag_of((unsigned)(t - 1));
      const unsigned char* rp = (t & 1) ? p0 : p1;   // plane of h_{t-1}
      const unsigned char* b0 = rp + oA0;
      const unsigned char* b1 = rp + oA1;
      const unsigned char* b2 = rp + oA2;
      const unsigned char* b3 = rp + oA3;
      u32x4 f0, f1, f2, f3, f4, f5, f6, f7;

      // ---- r17 clock-gate: calibrate over t=1..17, then gate at the
      // absolute schedule with Delta = 3/4 of the measured average.
      if (t == CAL_T0) {
        TA = rtc();
      } else if (t == CAL_T1) {
        TB = rtc();
        dstep = ((TB - TA) * 3) >> 6;    // (TB-TA)/16 * 3/4
      } else if (t > CAL_T1 && dstep > 0) {
        const unsigned long long gate =
            TB + (unsigned long long)(t - CAL_T1) * dstep;
        for (;;) {
          unsigned long long now = rtc();
          if (now >= gate) break;
          if (now + (dstep >> 3) < gate) __builtin_amdgcn_s_sleep(2);
        }
      }

      // r11/r15-proven single-phase poll: full loads + 32-tag verify
      for (;;) {
        ISSUE8(f0,f1,f2,f3,f4,f5,f6,f7, b0,b1,b2,b3);
        WAIT0();
        if (CHECK8(f0,f1,f2,f3,f4,f5,f6,f7, tauR)) break;
        __builtin_amdgcn_s_sleep(1);
      }
      MBLOCK(f0,f1,f2,f3,f4,f5,f6,f7)
    }

    // ---- kt-split partials for non-owned tiles -> red[buf] (r11-proven)
#pragma unroll
    for (int T = 0; T < 8; ++T) {
      const int rt = T >> 1, bt = T & 1;
      const int o = (rt & 2) | bt;
      if (o != wv) {
        const int slot = (wv > o) ? (wv - 1) : wv;
        red[buf][rt][bt][slot][lane] = acc[rt][bt];
      }
    }
    BARRIER();   // lgkm-only: store acks never gate the barrier

    // ---- owner waves 0..3: reduce both tiles, epilogue, one 16B store
    if (wv < 4) {
      f32x4 sA = acc[2 * u_c][bt_oo];
      f32x4 sB = acc[2 * u_c + 1][bt_oo];
#pragma unroll
      for (int pr = 0; pr < 7; ++pr) {
        sA += red[buf][2 * u_c][bt_oo][pr][lane];
        sB += red[buf][2 * u_c + 1][bt_oo][pr][lane];
      }
      const float xb = x_lds[bt_oo * 16 + l15][t];
      const float a0 = fast_tanh(sA[0] + xb * whxA.x + bhA.x);
      const float a1 = fast_tanh(sA[1] + xb * whxA.y + bhA.y);
      const float a2 = fast_tanh(sA[2] + xb * whxA.z + bhA.z);
      const float a3 = fast_tanh(sA[3] + xb * whxA.w + bhA.w);
      const float c0 = fast_tanh(sB[0] + xb * whxB.x + bhB.x);
      const float c1 = fast_tanh(sB[1] + xb * whxB.y + bhB.y);
      const float c2 = fast_tanh(sB[2] + xb * whxB.z + bhB.z);
      const float c3 = fast_tanh(sB[3] + xb * whxB.w + bhB.w);
      u32x4 stv;
      stv[0] = (((unsigned)f2bf(a0) | ((unsigned)f2bf(a1) << 16)) & ~1u) | tauW;
      stv[1] = (((unsigned)f2bf(a2) | ((unsigned)f2bf(a3) << 16)) & ~1u) | tauW;
      stv[2] = (((unsigned)f2bf(c0) | ((unsigned)f2bf(c1) << 16)) & ~1u) | tauW;
      stv[3] = (((unsigned)f2bf(c2) | ((unsigned)f2bf(c3) << 16)) & ~1u) | tauW;
      if (t & 1) *st1 = stv; else *st0 = stv;   // fire-and-forget write-through
    }
  }

  // ---- final projection (one WG per batch-group): out = h_last @ Wph + bp
  if (s != 0) return;
  {
    const unsigned tauF = tag_of(255u);   // = 0
    u32x4 hf[4][2];
    for (;;) {
#pragma unroll
      for (int i = 0; i < 4; ++i)
#pragma unroll
        for (int bt = 0; bt < 2; ++bt)
          hf[i][bt] = *(const volatile u32x4*)
              (p1 + ((size_t)((wv * 4 + i) * 16 + gb * 2 + bt) * 64 + lane) * 16);
      unsigned bad = 0;
#pragma unroll
      for (int i = 0; i < 4; ++i)
#pragma unroll
        for (int bt = 0; bt < 2; ++bt)
#pragma unroll
          for (int w = 0; w < 4; ++w) bad |= (hf[i][bt][w] ^ tauF) & 1u;
      if (__all((int)(bad == 0))) break;
      __builtin_amdgcn_s_sleep(2);
    }

    float pr0[NCLS], pr1[NCLS];
#pragma unroll
    for (int c = 0; c < NCLS; ++c) { pr0[c] = 0.f; pr1[c] = 0.f; }
#pragma unroll
    for (int i = 0; i < 4; ++i) {
      const int ks = wv * 4 + i;
#pragma unroll
      for (int bt = 0; bt < 2; ++bt) {
#pragma unroll
        for (int w = 0; w < 4; ++w) {
          unsigned word = hf[i][bt][w];
#pragma unroll
          for (int h2 = 0; h2 < 2; ++h2) {
            int j = 2 * w + h2;
            int k = ks * 32 + 4 * q + (j & 3) + 16 * (j >> 2);
            float hv = bf2f((unsigned short)(h2 ? (word >> 16) : (word & 0xffffu)));
            const float* wrow = Wph + (size_t)k * NCLS;
#pragma unroll
            for (int c = 0; c < NCLS; ++c) {
              if (bt == 0) pr0[c] += hv * wrow[c];
              else         pr1[c] += hv * wrow[c];
            }
          }
        }
      }
    }
#pragma unroll
    for (int c = 0; c < NCLS; ++c) {
      pr0[c] += __shfl_xor(pr0[c], 16, 64); pr0[c] += __shfl_xor(pr0[c], 32, 64);
      pr1[c] += __shfl_xor(pr1[c], 16, 64); pr1[c] += __shfl_xor(pr1[c], 32, 64);
    }
    float* projl = (float*)&red[0][0][0][0][0];   // reuse LDS
    if (q == 0) {
#pragma unroll
      for (int c = 0; c < NCLS; ++c) {
        projl[((wv * 2 + 0) * 16 + l15) * NCLS + c] = pr0[c];
        projl[((wv * 2 + 1) * 16 + l15) * NCLS + c] = pr1[c];
      }
    }
    __syncthreads();
    if (tid < 32 * NCLS) {
      int bl = tid / NCLS, c = tid - bl * NCLS;
      float sum = bp[c];
#pragma unroll
      for (int w = 0; w < 8; ++w)
        sum += projl[((w * 2 + (bl >> 4)) * 16 + (bl & 15)) * NCLS + c];
      out[(size_t)(gb * 32 + bl) * NCLS + c] = sum;
    }
  }
}

extern "C" void kernel_launch(void* const* d_in, const int* in_sizes, int n_in,
                              void* d_out, int out_size, void* d_ws, size_t ws_size,
                              hipStream_t stream) {
  const float* x   = (const float*)d_in[0];
  const float* Whx = (const float*)d_in[1];
  const float* Whh = (const float*)d_in[2];
  const float* Wph = (const float*)d_in[3];
  const float* bh  = (const float*)d_in[4];
  const float* bp  = (const float*)d_in[5];

  // no memset: tags self-validate against poison / stale replay data
  hipLaunchKernelGGL(rnn_r17, dim3(NWG), dim3(THREADS), 0, stream,
                     x, Whx, Whh, Wph, bh, bp,
                     (float*)d_out, (unsigned char*)d_ws);
}